// Round 2
// baseline (540.627 us; speedup 1.0000x reference)
//
#include <hip/hip_runtime.h>
#include <hip/hip_bf16.h>

#define NB 8192   // batch
#define ND 1024   // feature dim (== bytes per row in fp8)

typedef __attribute__((ext_vector_type(8))) int   i32x8;
typedef __attribute__((ext_vector_type(4))) int   i32x4;
typedef __attribute__((ext_vector_type(4))) float f32x4;

__device__ __forceinline__ void async16(const void* g, void* l) {
  __builtin_amdgcn_global_load_lds(
      (const __attribute__((address_space(1))) void*)g,
      (__attribute__((address_space(3))) void*)l,
      16, 0, 0);
}

// ---------------------------------------------------------------------------
// L2-normalize rows of visual/textual feats (f32 in) -> fp8 e4m3 out.
// grid (NB, 2), block 256. Each thread owns 4 contiguous floats -> 4 fp8 bytes.
// Block (0,0) additionally converts the noisy mask (bool-byte vs int32
// auto-detect) to float.
__global__ void norm_cast(const float* __restrict__ vis,
                          const float* __restrict__ txt,
                          unsigned char* __restrict__ vb,
                          unsigned char* __restrict__ tb,
                          const unsigned char* __restrict__ rawmask,
                          float* __restrict__ nmask) {
  const float* src = blockIdx.y ? txt : vis;
  unsigned char* dst = blockIdx.y ? tb : vb;
  int row = blockIdx.x;
  int t = threadIdx.x;
  float4 x = ((const float4*)(src + (size_t)row * ND))[t];
  float ss = x.x * x.x + x.y * x.y + x.z * x.z + x.w * x.w;
  #pragma unroll
  for (int m = 32; m; m >>= 1) ss += __shfl_xor(ss, m);
  __shared__ float sred[4];
  if ((t & 63) == 0) sred[t >> 6] = ss;
  __syncthreads();
  float tot = sred[0] + sred[1] + sred[2] + sred[3];
  float inv = 1.0f / fmaxf(sqrtf(tot), 1e-12f);
  int p = 0;
  p = __builtin_amdgcn_cvt_pk_fp8_f32(x.x * inv, x.y * inv, p, false);
  p = __builtin_amdgcn_cvt_pk_fp8_f32(x.z * inv, x.w * inv, p, true);
  ((int*)dst)[(size_t)row * (ND / 4) + t] = p;

  // mask prep, piggybacked on one block (runs before gemm in stream order)
  if (blockIdx.x == 0 && blockIdx.y == 0) {
    // int32 layout => every byte at (i%4)!=0 is 0 over the first NB bytes;
    // random 0/1 bool bytes make that impossible.
    int any = 0;
    for (int i = t; i < NB; i += 256)
      if ((i & 3) != 0 && rawmask[i] != 0) any = 1;
    #pragma unroll
    for (int m = 32; m; m >>= 1) any |= __shfl_xor(any, m);
    __shared__ int flag[4];
    if ((t & 63) == 0) flag[t >> 6] = any;
    __syncthreads();
    int isbyte = flag[0] | flag[1] | flag[2] | flag[3];
    if (isbyte) {
      for (int i = t; i < NB; i += 256) nmask[i] = rawmask[i] ? 1.0f : 0.0f;
    } else {
      const int* ri = (const int*)rawmask;
      for (int i = t; i < NB; i += 256) nmask[i] = ri[i] ? 1.0f : 0.0f;
    }
  }
}

// ---------------------------------------------------------------------------
// Fused MX-fp8 GEMM + masked-exp row-sum.
// sim = Vn @ Tn^T, both [NB, ND] fp8 e4m3 row-major (K-contiguous, NT GEMM).
// Block: 128x128 sim tile; 4 waves, each a 64x64 quadrant of 4x4
// mfma_scale_f32_16x16x128_f8f6f4 (fmt fp8, scales == 1.0 via e8m0=127).
// K-loop: 8 iterations of BK=128 (bytes == elements).
//
// LDS: row-major 128 B/row with global-side XOR chunk swizzle: LDS 16B-chunk
// position p of row r holds global chunk p^(r&7). Staging keeps the
// global_load_lds wave-uniform-base + lane*16 contract; fragment reads
// (2 x ds_read_b128 per 32B lane fragment) land 2 lanes/bank = conflict-free.
//
// A/B lane layout for 16x16x128 f8f6f4: row/col = lane&15,
// k = (lane>>4)*32 + e  (each lane's 32 elements = exactly one 32-wide MX
// scale block -- forced by the one-scale-byte-per-lane encoding).
// C/D layout (shape-determined, m121-m128): col = lane&15, row = quad*4+reg.
__global__ __launch_bounds__(256) void gemm_fused(
    const unsigned char* __restrict__ vb, const unsigned char* __restrict__ tb,
    const float* __restrict__ nmask, float* __restrict__ partial) {
  __shared__ char As[128 * 128];
  __shared__ char Bs[128 * 128];
  __shared__ float part2[128][2];

  const int bx = blockIdx.x, by = blockIdx.y;
  const int i0 = by * 128, j0 = bx * 128;
  const int t = threadIdx.x;
  const int w = t >> 6;          // wave 0..3
  const int l = t & 63;
  const int quad = l >> 4;
  const int l15 = l & 15;
  const int x7 = l15 & 7;        // r&7 for this lane's fragment rows
  const int wm = w >> 1, wn = w & 1;
  const int rw = wm * 64, cw = wn * 64;
  const int SC = 0x7f7f7f7f;     // e8m0 127 = scale 1.0, all byte positions

  // staging: lane l covers row (l>>3) of its 8-row group, LDS position l&7,
  // fetching global 16B chunk (l&7)^(l>>3)
  const int lrow = l >> 3;
  const int lchunk = (l & 7) ^ lrow;
  const unsigned char* Ag = vb + (size_t)(i0 + w * 32 + lrow) * ND + lchunk * 16;
  const unsigned char* Bg = tb + (size_t)(j0 + w * 32 + lrow) * ND + lchunk * 16;
  char* AsB = As + w * 32 * 128;
  char* BsB = Bs + w * 32 * 128;

  f32x4 acc[4][4] = {};

  for (int kb = 0; kb < ND; kb += 128) {
    #pragma unroll
    for (int q = 0; q < 4; ++q) {
      async16(Ag + kb + q * 8 * ND, AsB + q * 1024);
      async16(Bg + kb + q * 8 * ND, BsB + q * 1024);
    }
    __syncthreads();  // compiler drains vmcnt before s_barrier

    i32x8 bfr[4];
    #pragma unroll
    for (int ni = 0; ni < 4; ++ni) {
      int r = cw + ni * 16 + l15;
      int p0 = ((2 * quad) ^ x7) * 16;
      i32x4 lo = *(const i32x4*)&Bs[r * 128 + p0];
      i32x4 hi = *(const i32x4*)&Bs[r * 128 + (p0 ^ 16)];
      bfr[ni] = __builtin_shufflevector(lo, hi, 0, 1, 2, 3, 4, 5, 6, 7);
    }
    #pragma unroll
    for (int mi = 0; mi < 4; ++mi) {
      int r = rw + mi * 16 + l15;
      int p0 = ((2 * quad) ^ x7) * 16;
      i32x4 lo = *(const i32x4*)&As[r * 128 + p0];
      i32x4 hi = *(const i32x4*)&As[r * 128 + (p0 ^ 16)];
      i32x8 afr = __builtin_shufflevector(lo, hi, 0, 1, 2, 3, 4, 5, 6, 7);
      #pragma unroll
      for (int ni = 0; ni < 4; ++ni)
        acc[mi][ni] = __builtin_amdgcn_mfma_scale_f32_16x16x128_f8f6f4(
            afr, bfr[ni], acc[mi][ni], /*cbsz=fp8*/0, /*blgp=fp8*/0,
            0, SC, 0, SC);
    }
    __syncthreads();
  }

  // Epilogue: val = exp(sim/T)*max(n_row,n_col); row-sum over the 128 cols.
  const float SCALE = 20.60992915555662f;  // log2(e)/0.07
  float ncol[4];
  #pragma unroll
  for (int ni = 0; ni < 4; ++ni) ncol[ni] = nmask[j0 + cw + ni * 16 + l15];

  #pragma unroll
  for (int mi = 0; mi < 4; ++mi) {
    float nrow[4], rowacc[4] = {0.f, 0.f, 0.f, 0.f};
    #pragma unroll
    for (int r = 0; r < 4; ++r) nrow[r] = nmask[i0 + rw + mi * 16 + quad * 4 + r];
    #pragma unroll
    for (int ni = 0; ni < 4; ++ni) {
      #pragma unroll
      for (int r = 0; r < 4; ++r)
        rowacc[r] += exp2f(acc[mi][ni][r] * SCALE) * fmaxf(nrow[r], ncol[ni]);
    }
    #pragma unroll
    for (int r = 0; r < 4; ++r) {
      float v = rowacc[r];
      v += __shfl_xor(v, 1); v += __shfl_xor(v, 2);
      v += __shfl_xor(v, 4); v += __shfl_xor(v, 8);
      if (l15 == 0) part2[rw + mi * 16 + quad * 4 + r][wn] = v;
    }
  }
  __syncthreads();
  if (t < 128)
    partial[(size_t)bx * NB + i0 + t] = part2[t][0] + part2[t][1];
}

// ---------------------------------------------------------------------------
// loss = mean_i log(sum_c partial[c][i] + 1e-8). 32 blocks x 256 threads.
__global__ void finalize(const float* __restrict__ partial, float* __restrict__ out) {
  int r = blockIdx.x * 256 + threadIdx.x;
  float s = 0.f;
  #pragma unroll 4
  for (int c = 0; c < 64; ++c) s += partial[(size_t)c * NB + r];
  float lg = logf(s + 1e-8f);
  #pragma unroll
  for (int m = 32; m; m >>= 1) lg += __shfl_xor(lg, m);
  __shared__ float sred[4];
  if ((threadIdx.x & 63) == 0) sred[threadIdx.x >> 6] = lg;
  __syncthreads();
  if (threadIdx.x == 0)
    atomicAdd(out, (sred[0] + sred[1] + sred[2] + sred[3]) * (1.0f / NB));
}

// ---------------------------------------------------------------------------
extern "C" void kernel_launch(void* const* d_in, const int* in_sizes, int n_in,
                              void* d_out, int out_size, void* d_ws, size_t ws_size,
                              hipStream_t stream) {
  const float* vis = (const float*)d_in[0];
  const float* txt = (const float*)d_in[1];
  // d_in[2] transport_matrix: unused. d_in[3] clean mask: unused.
  const unsigned char* noisy = (const unsigned char*)d_in[4];
  float* out = (float*)d_out;

  char* ws = (char*)d_ws;
  unsigned char* vb = (unsigned char*)ws;                          // 8 MB fp8
  unsigned char* tb = (unsigned char*)(ws + ((size_t)8 << 20));    // 8 MB fp8
  float* nmask = (float*)(ws + ((size_t)16 << 20));                // 32 KB
  float* partial = (float*)(ws + ((size_t)16 << 20) + (64 << 10)); // 2 MB

  hipMemsetAsync(d_out, 0, sizeof(float), stream);
  norm_cast<<<dim3(NB, 2), 256, 0, stream>>>(vis, txt, vb, tb, noisy, nmask);
  gemm_fused<<<dim3(NB / 128, NB / 128), 256, 0, stream>>>(vb, tb, nmask, partial);
  finalize<<<NB / 256, 256, 0, stream>>>(partial, out);
}